// Round 24
// baseline (66.728 us; speedup 1.0000x reference)
//
#include <hip/hip_runtime.h>
#include <stdint.h>

#define BN_ 8192
#define DK_ 256
#define LOG2E 1.4426950408889634f
// int8 quantization: q = round(127*x); dot fits i32 exactly
#define INVQ (1.0f / 16129.0f)          // 1/127^2: acc -> natural-units sim
#define KQ   (LOG2E / 16129.0f)          // acc -> log2-units sim

typedef __attribute__((ext_vector_type(4))) float f32x4;
typedef __attribute__((ext_vector_type(4))) int i32x4;

// async global->LDS, 16B/lane; LDS dest wave-uniform base + lane*16, global src per-lane
#define GLD16(gp, lp)                                                   \
  __builtin_amdgcn_global_load_lds(                                     \
      (__attribute__((address_space(1))) void*)(gp),                    \
      (__attribute__((address_space(3))) void*)(lp), 16, 0, 0)

#define BAR() __builtin_amdgcn_s_barrier()
#define VM4() asm volatile("s_waitcnt vmcnt(4)" ::: "memory")
#define VM0() asm volatile("s_waitcnt vmcnt(0)" ::: "memory")

// ---------------- Kernel 1: row-normalize fp32 -> int8 (x127); also zeroes sumexp ----------------
__global__ __launch_bounds__(256) void norm_kernel(
    const float* __restrict__ hf, const float* __restrict__ lf,
    const float* __restrict__ af, unsigned char* __restrict__ qbase,
    float* __restrict__ sumexp) {
  const int tid = threadIdx.x;
  if (blockIdx.x < 16) {   // folded memset of sumexp[16384]
    f32x4 z = {0.f, 0.f, 0.f, 0.f};
    *(f32x4*)(sumexp + blockIdx.x * 1024 + tid * 4) = z;
  }
  const int w = tid >> 6, lane = tid & 63;
  const int grow = blockIdx.x * 4 + w;
  const int m = grow >> 13;
  const int r = grow & (BN_ - 1);
  const float* src = (m == 0) ? hf : (m == 1) ? lf : af;
  unsigned char* dst = qbase + (size_t)m * BN_ * DK_;
  const float4 v = ((const float4*)(src + (size_t)r * DK_))[lane];
  float ss = v.x * v.x + v.y * v.y + v.z * v.z + v.w * v.w;
#pragma unroll
  for (int mk = 32; mk >= 1; mk >>= 1) ss += __shfl_xor(ss, mk, 64);
  const float inv = 127.0f / fmaxf(sqrtf(ss), 1e-8f);
  const int q0 = (int)rintf(v.x * inv), q1 = (int)rintf(v.y * inv);
  const int q2 = (int)rintf(v.z * inv), q3 = (int)rintf(v.w * inv);
  const unsigned pk = (q0 & 255) | ((q1 & 255) << 8) | ((q2 & 255) << 16) |
                      ((unsigned)(q3 & 255) << 24);
  *(unsigned*)(dst + (size_t)r * DK_ + lane * 4) = pk;
}

// ---------------- Kernel 2: barrier-free int8-GEMM + exp2-row-sum + diag ----------------
// R19/R23 champion unit (16 MFMA + 4 ds_read + 4 stage + vmcnt(4), no
// setprio) at HIGHER OCCUPANCY without thinning the wave (R21's mistake):
// 4-wave blocks (1wr x 4wc), wave tile stays 64x64, A panel 64 rows (16KB),
// per-wave 2-slot B (8KB). LDS 48KB -> 3 blocks/CU = 3 waves/SIMD (+50%
// independent streams vs R23's 2) to fill the measured ~50% dependency-idle.
// Grid 1024 = 256 panels x 4 col-quarters (8 ct each).
// Hazard ledger = R19's (intra-wave only): RAW -- VM4 after STAGEB(u+1)
// leaves <=4 outstanding -> B(u) retired; WAR -- slot (u+1)&1 last read at
// u-1, reads lgkm-drained before MFMA(u-1) which precedes the stage issue.
__global__ __launch_bounds__(256, 2) void gemm_lse_kernel(
    const unsigned char* __restrict__ hl, const unsigned char* __restrict__ an,
    float* __restrict__ sumexp /*[16384]*/, float* __restrict__ diag /*[16384]*/) {
  extern __shared__ char lds[];  // 48KB: A 16KB + 4 waves x 8KB B

  const int tid = threadIdx.x;          // 0..255
  const int lane = tid & 63, w = tid >> 6;   // w == wc (1 wr)
  const int lmod = lane & 15, lhalf = lane >> 4;

  const int bid = blockIdx.x;           // 0..1023
  const int swz = (bid & 7) * 128 + (bid >> 3);  // bijective on 1024, XCD-grouping
  const int mt = swz >> 2;              // A panel 0..255 (64 rows each)
  const int cq = swz & 3;               // col quarter (2048 cols, 8 ct)

  // ---- A cooperative stage: 64 rows x 16 slots, phys16 = s ^ (row&15) ----
  // 256 thr x 16B x 4 rounds (row += 16 each; row&15 invariant = tid>>4)
  const int aswz = 16 * ((tid & 15) ^ ((tid >> 4) & 15));
  const unsigned char* aG = hl + (size_t)(mt * 64 + (tid >> 4)) * DK_ + aswz;
  char* aD = lds + tid * 16;
  GLD16(aG, aD);
  GLD16(aG + 4096, aD + 4096);
  GLD16(aG + 8192, aD + 8192);
  GLD16(aG + 12288, aD + 12288);

  // ---- B private staging constants (R16/R19-verified 64-row slice layout) ----
  const int slog16 = 16 * ((lane & 3) ^ ((lane >> 3) & 3));
  const unsigned char* bB =
      an + (size_t)(cq * 2048 + w * 64 + (lane >> 2)) * DK_ + slog16;
  char* ldsB = lds + 16384 + w * 8192 + lane * 16;

#define STAGEB(uu)                                                       \
  do {                                                                   \
    const int ct_ = (uu) >> 2, ku_ = (uu) & 3;                           \
    const unsigned char* g_ = bB + ct_ * 65536 + ku_ * 64;               \
    char* d_ = ldsB + ((uu) & 1) * 4096;                                 \
    GLD16(g_, d_);                                                       \
    GLD16(g_ + 4096, d_ + 1024);                                         \
    GLD16(g_ + 8192, d_ + 2048);                                         \
    GLD16(g_ + 12288, d_ + 3072);                                        \
  } while (0)

  STAGEB(0);
  VM4();   // 8 outstanding (4 A + 4 B0) -> <=4 left: all A loads retired
  BAR();   // the kernel's ONLY barrier: A collectively resident

  // ---- hoist all A fragments (1 wr: wave rows == panel rows) ----
  i32x4 afr[4][4];
  {
    const char* aR = lds + lmod * 256;
#pragma unroll
    for (int ku = 0; ku < 4; ++ku)
#pragma unroll
      for (int m = 0; m < 4; ++m)
        afr[ku][m] = *(const i32x4*)(aR + m * 4096 + 16 * ((ku * 4 + lhalf) ^ lmod));
  }

  const int rdoffB = lmod * 64 + 16 * (lhalf ^ ((lmod >> 1) & 3));
  const char* ldsBr = lds + 16384 + w * 8192;

#define MFMA16(KU)                                                       \
  _Pragma("unroll") for (int m = 0; m < 4; ++m)                          \
  _Pragma("unroll") for (int n = 0; n < 4; ++n)                          \
      acc[m][n] = __builtin_amdgcn_mfma_i32_16x16x64_i8(                 \
          afr[KU][m], bf[n], acc[m][n], 0, 0, 0)

  // ---- diag geometry: panel rows C0..C0+63; diag tile is acc[m][m] ----
  const int p = mt >> 7;
  const int C0 = (mt & 127) * 64;
  const bool dWave = (cq == (C0 >> 11)) && (w == ((C0 >> 6) & 3));
  const int ctD = (C0 & 2047) >> 8;

  float rsum[4][4];
#pragma unroll
  for (int m = 0; m < 4; ++m)
#pragma unroll
    for (int r = 0; r < 4; ++r) rsum[m][r] = 0.0f;

#pragma unroll 1
  for (int ct = 0; ct < 8; ++ct) {
    i32x4 acc[4][4];
#pragma unroll
    for (int m = 0; m < 4; ++m)
#pragma unroll
      for (int n = 0; n < 4; ++n) acc[m][n] = i32x4{0, 0, 0, 0};

#pragma unroll
    for (int ku = 0; ku < 4; ++ku) {
      const int u = ct * 4 + ku;
      if (u < 31) {
        STAGEB(u + 1);
        VM4();   // my B(u) landed (only B(u+1)'s 4 loads may remain)
      } else {
        VM0();   // last unit: drain B(31)
      }
      const char* Lb = ldsBr + (u & 1) * 4096;
      i32x4 bf[4];
#pragma unroll
      for (int n = 0; n < 4; ++n) bf[n] = *(const i32x4*)(Lb + n * 1024 + rdoffB);
      MFMA16(ku);
    }

    // ---- tile epilogue: diag (rare, compile-time indices) + exp2 ----
    if (dWave && ct == ctD) {
#pragma unroll
      for (int m = 0; m < 4; ++m)
#pragma unroll
        for (int r = 0; r < 4; ++r)
          if (lmod == lhalf * 4 + r)
            diag[p * BN_ + C0 + m * 16 + lmod] = (float)acc[m][m][r] * INVQ;
    }
#pragma unroll
    for (int m = 0; m < 4; ++m)
#pragma unroll
      for (int n = 0; n < 4; ++n)
#pragma unroll
        for (int r = 0; r < 4; ++r)
          rsum[m][r] += __builtin_amdgcn_exp2f((float)acc[m][n][r] * KQ);
  }

  // ---- final: reduce across 16 col-lanes, then atomicAdd
  // (4 wc waves x 4 cq blocks contribute to each row) ----
#pragma unroll
  for (int m = 0; m < 4; ++m)
#pragma unroll
    for (int r = 0; r < 4; ++r) {
      float v = rsum[m][r];
      v += __shfl_xor(v, 1, 64);
      v += __shfl_xor(v, 2, 64);
      v += __shfl_xor(v, 4, 64);
      v += __shfl_xor(v, 8, 64);
      if (lmod == 0)
        atomicAdd(&sumexp[p * BN_ + C0 + m * 16 + lhalf * 4 + r], v);
    }
#undef STAGEB
#undef MFMA16
}

// ---------------- Kernel 3: CE = mean(log(sumexp) - diag) ----------------
__global__ __launch_bounds__(1024) void finalize_kernel(
    const float* __restrict__ sumexp, const float* __restrict__ diag,
    float* __restrict__ out) {
  const int tid = threadIdx.x;
  float s = 0.0f;
  for (int i = tid; i < 2 * BN_; i += 1024) s += logf(sumexp[i]) - diag[i];
#pragma unroll
  for (int mk = 32; mk >= 1; mk >>= 1) s += __shfl_xor(s, mk, 64);
  __shared__ float red[16];
  if ((tid & 63) == 0) red[tid >> 6] = s;
  __syncthreads();
  if (tid == 0) {
    float t = 0.f;
#pragma unroll
    for (int j = 0; j < 16; ++j) t += red[j];
    out[0] = t * (1.0f / (float)BN_);
  }
}

extern "C" void kernel_launch(void* const* d_in, const int* in_sizes, int n_in,
                              void* d_out, int out_size, void* d_ws, size_t ws_size,
                              hipStream_t stream) {
  const float* hf = (const float*)d_in[0];
  const float* lf = (const float*)d_in[1];
  const float* af = (const float*)d_in[2];

  char* ws = (char*)d_ws;
  const size_t nmat = (size_t)BN_ * DK_;                 // 2MB as i8
  unsigned char* qbase = (unsigned char*)ws;             // hq(2MB) lq(2MB) aq(2MB)
  unsigned char* hl = qbase;                             // stacked A [16384][256]
  unsigned char* an = qbase + 2 * nmat;
  float* sumexp = (float*)(ws + 3 * nmat);               // 64 KB [16384]
  float* diag = sumexp + 2 * BN_;                        // 64 KB [16384]

  hipFuncSetAttribute((const void*)gemm_lse_kernel,
                      hipFuncAttributeMaxDynamicSharedMemorySize, 49152);

  norm_kernel<<<(3 * BN_) / 4, 256, 0, stream>>>(hf, lf, af, qbase, sumexp);
  gemm_lse_kernel<<<1024, 256, 49152, stream>>>(hl, an, sumexp, diag);
  finalize_kernel<<<1, 1024, 0, stream>>>(sumexp, diag, (float*)d_out);
}